// Round 1
// baseline (277.189 us; speedup 1.0000x reference)
//
#include <hip/hip_runtime.h>
#include <hip/hip_bf16.h>
#include <math.h>

// ---------------- problem constants ----------------
constexpr int BS   = 512;
constexpr int TOK  = 36,  DM = 768;
constexpr int EMB  = 256;
constexpr int NBS  = 1536;   // BS * NSENT
constexpr int NPOS = 300;    // HIST*H*W
constexpr int LIN  = 5184;   // FM * 9 * 9
constexpr int TFD  = 768;    // 12 taps * 64 filters
constexpr int KSPLIT = 27, KCH = 192;   // 27*192 = 5184

// ---------------- workspace layout (floats) ----------------
constexpr size_t OFF_XK   = 0;                               // 1536*768
constexpr size_t OFF_XV   = OFF_XK + (size_t)NBS * DM;       // 1536*768
constexpr size_t OFF_P    = OFF_XV + (size_t)NBS * DM;       // 25*768
constexpr size_t OFF_C0   = OFF_P  + 25 * 768;               // 64
constexpr size_t OFF_FL   = OFF_C0 + 64;                     // 64 (int)
constexpr size_t OFF_W2   = OFF_FL + 64;                     // 256*768
constexpr size_t OFF_RD   = OFF_W2 + 256 * 768;              // 25*768
constexpr size_t OFF_DT   = OFF_RD + 25 * 768;               // 1536*25 -> 38400
constexpr size_t OFF_V    = OFF_DT + 38400;                  // 1536*256
constexpr size_t OFF_VW   = OFF_V  + (size_t)NBS * EMB;      // 1536*768
constexpr size_t OFF_Y    = OFF_VW + (size_t)NBS * TFD;      // 512*5184
constexpr size_t OFF_PART = OFF_Y  + (size_t)BS * LIN;       // 27*512*256
constexpr size_t OFF_H1   = OFF_PART + (size_t)KSPLIT * BS * 256; // 512*256

// ---------------- K0: repack conv_w -> W2[c][tap*64+f]; flags/c0 ----------------
__global__ __launch_bounds__(256) void k0_prep(
    const float* __restrict__ conv_w, const float* __restrict__ sprite,
    const float* __restrict__ bk, float* __restrict__ W2,
    float* __restrict__ c0, int* __restrict__ flags)
{
    if (blockIdx.x < 768) {
        int d = blockIdx.x * 256 + threadIdx.x;         // dest index, 196608 total
        int c = d / 768, r = d - c * 768;
        int tap = r >> 6, f = r & 63;
        int t4 = tap / 3, j = tap - t4 * 3;
        W2[d] = conv_w[((t4 * 768 + j * 256 + c) << 6) + f];
    } else {
        int o = threadIdx.x;
        if (o < 25) {
            float s = 0.f, cc = 0.f;
            for (int c = 0; c < 256; ++c) {
                float e = sprite[o * 256 + c];
                s += e; cc += e * bk[c];
            }
            flags[o] = (s != 0.0f) ? 1 : 0;
            c0[o] = cc;
        }
    }
}

// ---------------- K1: per-(b,s) token softmax + weighted sums ----------------
__global__ __launch_bounds__(256) void k1_temb(
    const float* __restrict__ temb, const float* __restrict__ Wks,
    const float* __restrict__ Wvs, float* __restrict__ xk, float* __restrict__ xv)
{
    __shared__ float sWk[DM], sWv[DM];
    __shared__ float chunk[12 * DM];
    __shared__ float sk[12], sv[12];
    int tid = threadIdx.x;
    int bs  = blockIdx.x;
    const float* src = temb + (size_t)bs * TOK * DM;
    for (int i = tid; i < DM; i += 256) { sWk[i] = Wks[i]; sWv[i] = Wvs[i]; }

    float mk = -INFINITY, mv = -INFINITY, Zk = 0.f, Zv = 0.f;
    float ak[3] = {0.f, 0.f, 0.f}, av[3] = {0.f, 0.f, 0.f};
    int lane = tid & 63, wv = tid >> 6;

    for (int c = 0; c < 3; ++c) {
        __syncthreads();                          // chunk free + sWk visible
        const float4* s4 = (const float4*)(src + (size_t)c * 12 * DM);
        float4* d4 = (float4*)chunk;
        #pragma unroll
        for (int i = 0; i < 9; ++i) d4[tid + i * 256] = s4[tid + i * 256];
        __syncthreads();
        // scores: wave wv owns tokens wv*3 .. wv*3+2
        #pragma unroll
        for (int tt = 0; tt < 3; ++tt) {
            int t = wv * 3 + tt;
            const float* row = chunk + t * DM;
            float pk = 0.f, pv = 0.f;
            for (int d = lane; d < DM; d += 64) {
                float x = row[d];
                pk += x * sWk[d]; pv += x * sWv[d];
            }
            #pragma unroll
            for (int off = 32; off; off >>= 1) {
                pk += __shfl_down(pk, off);
                pv += __shfl_down(pv, off);
            }
            if (lane == 0) { sk[t] = pk; sv[t] = pv; }
        }
        __syncthreads();
        // online softmax update
        float cmk = sk[0], cmv = sv[0];
        #pragma unroll
        for (int t = 1; t < 12; ++t) { cmk = fmaxf(cmk, sk[t]); cmv = fmaxf(cmv, sv[t]); }
        float nmk = fmaxf(mk, cmk), nmv = fmaxf(mv, cmv);
        float rk = expf(mk - nmk), rv = expf(mv - nmv);  // 0 on first chunk
        mk = nmk; mv = nmv;
        float wk[12], wvv[12], swk = 0.f, swv = 0.f;
        #pragma unroll
        for (int t = 0; t < 12; ++t) {
            wk[t]  = expf(sk[t] - nmk); swk += wk[t];
            wvv[t] = expf(sv[t] - nmv); swv += wvv[t];
        }
        Zk = Zk * rk + swk; Zv = Zv * rv + swv;
        float sxk[3] = {0.f, 0.f, 0.f}, sxv[3] = {0.f, 0.f, 0.f};
        #pragma unroll
        for (int t = 0; t < 12; ++t) {
            #pragma unroll
            for (int j = 0; j < 3; ++j) {
                float x = chunk[t * DM + tid + j * 256];
                sxk[j] += wk[t] * x; sxv[j] += wvv[t] * x;
            }
        }
        #pragma unroll
        for (int j = 0; j < 3; ++j) {
            ak[j] = ak[j] * rk + sxk[j];
            av[j] = av[j] * rv + sxv[j];
        }
    }
    float izk = 1.f / Zk, izv = 1.f / Zv;
    #pragma unroll
    for (int j = 0; j < 3; ++j) {
        xk[(size_t)bs * DM + tid + j * 256] = ak[j] * izk;
        xv[(size_t)bs * DM + tid + j * 256] = av[j] * izv;
    }
}

// ---------------- generic fp32 tiled GEMM ----------------
// C[m,n] = sum_k A[m,k] * B(k,n)   (BT=0: B is KxN row-major; BT=1: B is NxK)
// grid.z = split-K slice; kb = z*klen; C += z*czstride
template<int BM, int BN, int BT, int BIAS, int ACT>
__global__ __launch_bounds__(256) void gemm_f32(
    const float* __restrict__ A, int lda,
    const float* __restrict__ B, int ldb,
    const float* __restrict__ bias,
    float* __restrict__ C, int ldc, size_t czstride,
    int M, int N, int K, int klen)
{
    constexpr int MR = BM / 16, NR = BN / 16;
    __shared__ float As[16][BM + 4];
    __shared__ float Bs[16][BN + 4];
    int tid = threadIdx.x;
    int bm = blockIdx.x * BM, bn = blockIdx.y * BN;
    int kb = blockIdx.z * klen;
    C += blockIdx.z * czstride;
    int tn = tid & 15, tm = tid >> 4;
    float acc[MR][NR];
    #pragma unroll
    for (int i = 0; i < MR; ++i)
        #pragma unroll
        for (int j = 0; j < NR; ++j) acc[i][j] = 0.f;

    for (int k0 = kb; k0 < kb + klen; k0 += 16) {
        // A tile (BM x 16), float4 along k
        for (int i4 = tid; i4 < BM * 4; i4 += 256) {
            int r = i4 >> 2, c4 = (i4 & 3) << 2;
            float4 val = {0.f, 0.f, 0.f, 0.f};
            if (bm + r < M) val = *(const float4*)(A + (size_t)(bm + r) * lda + k0 + c4);
            As[c4 + 0][r] = val.x; As[c4 + 1][r] = val.y;
            As[c4 + 2][r] = val.z; As[c4 + 3][r] = val.w;
        }
        // B tile (16 x BN)
        if (BT == 0) {
            for (int i4 = tid; i4 < BN * 4; i4 += 256) {
                int nn = (i4 % (BN / 4)) << 2, kk = i4 / (BN / 4);
                float4 val = {0.f, 0.f, 0.f, 0.f};
                if (bn + nn + 3 < N) val = *(const float4*)(B + (size_t)(k0 + kk) * ldb + bn + nn);
                *(float4*)&Bs[kk][nn] = val;
            }
        } else {
            for (int i4 = tid; i4 < BN * 4; i4 += 256) {
                int n = i4 >> 2, c4 = (i4 & 3) << 2;
                float4 val = {0.f, 0.f, 0.f, 0.f};
                if (bn + n < N) val = *(const float4*)(B + (size_t)(bn + n) * ldb + k0 + c4);
                Bs[c4 + 0][n] = val.x; Bs[c4 + 1][n] = val.y;
                Bs[c4 + 2][n] = val.z; Bs[c4 + 3][n] = val.w;
            }
        }
        __syncthreads();
        #pragma unroll
        for (int kk = 0; kk < 16; ++kk) {
            float a[MR], b[NR];
            #pragma unroll
            for (int i = 0; i < MR; ++i) a[i] = As[kk][tm * MR + i];
            #pragma unroll
            for (int j = 0; j < NR; ++j) b[j] = Bs[kk][tn * NR + j];
            #pragma unroll
            for (int i = 0; i < MR; ++i)
                #pragma unroll
                for (int j = 0; j < NR; ++j) acc[i][j] += a[i] * b[j];
        }
        __syncthreads();
    }
    #pragma unroll
    for (int i = 0; i < MR; ++i) {
        int row = bm + tm * MR + i;
        if (row >= M) continue;
        #pragma unroll
        for (int j = 0; j < NR; ++j) {
            int col = bn + tn * NR + j;
            if (col >= N) continue;
            float v = acc[i][j];
            if (BIAS) v += bias[col];
            if (ACT)  v = v > 0.f ? v : 0.01f * v;
            C[(size_t)row * ldc + col] = v;
        }
    }
}

// ---------------- K4: wts + factored conv + transpose-flatten + lrelu ----------------
__global__ __launch_bounds__(256) void k4_y(
    const int* __restrict__ state, const float* __restrict__ dt,
    const int* __restrict__ flags, const float* __restrict__ vW,
    const float* __restrict__ rowdot, const float* __restrict__ conv_b,
    float* __restrict__ y)
{
    int b = blockIdx.x, tid = threadIdx.x;
    __shared__ float s_vW[3 * TFD];
    __shared__ float s_w[3][NPOS + 4];
    __shared__ int   s_avt[NPOS + 4];
    __shared__ float s_y[81 * 65];

    const float4* vs = (const float4*)(vW + (size_t)b * 3 * TFD);
    float4* vd = (float4*)s_vW;
    for (int i = tid; i < 576; i += 256) vd[i] = vs[i];

    for (int code = tid; code < NPOS; code += 256) {
        const int* st = state + ((size_t)b * NPOS + code) * 4;
        int o0 = st[0], o1 = st[1], o2 = st[2], avi = st[3];
        int cnt = flags[o0] + flags[o1] + flags[o2];
        s_avt[code] = avi;
        float w0 = 0.f, w1 = 0.f, w2 = 0.f;
        if (cnt > 0) {
            const float* d0 = dt + (size_t)b * 75;
            float inv = 1.0f / (16.0f * (float)cnt);
            float q0 = (d0[o0]      + d0[o1]      + d0[o2])      * inv;
            float q1 = (d0[25 + o0] + d0[25 + o1] + d0[25 + o2]) * inv;
            float q2 = (d0[50 + o0] + d0[50 + o1] + d0[50 + o2]) * inv;
            float m = fmaxf(q0, fmaxf(q1, q2));
            float e0 = expf(q0 - m), e1 = expf(q1 - m), e2 = expf(q2 - m);
            float is = 1.0f / (6.0f * (e0 + e1 + e2));   // folds att/3 and st/2
            w0 = e0 * is; w1 = e1 * is; w2 = e2 * is;
        }
        s_w[0][code] = w0; s_w[1][code] = w1; s_w[2][code] = w2;
    }
    __syncthreads();

    int f = tid & 63;
    float cb = conv_b[f];
    for (int p = tid >> 6; p < 81; p += 4) {
        int oh = p / 9, ow = p - oh * 9;
        float acc = cb;
        #pragma unroll
        for (int kh = 0; kh < 2; ++kh)
        #pragma unroll
        for (int kw = 0; kw < 2; ++kw) {
            int bc = 3 * ((oh + kh) * 10 + (ow + kw));
            int tbase = ((kh * 2 + kw) * 3) * 64 + f;
            #pragma unroll
            for (int j = 0; j < 3; ++j) {
                int code = bc + j;
                int tf = tbase + j * 64;
                acc += s_w[0][code] * s_vW[tf]
                     + s_w[1][code] * s_vW[TFD + tf]
                     + s_w[2][code] * s_vW[2 * TFD + tf];
                acc += 0.5f * rowdot[(size_t)s_avt[code] * TFD + tf];
            }
        }
        acc = acc > 0.f ? acc : 0.01f * acc;
        s_y[p * 65 + f] = acc;
    }
    __syncthreads();
    for (int i = tid; i < LIN; i += 256) {       // y_flat[b, f*81 + p]
        int ff = i / 81, pp = i - ff * 81;
        y[(size_t)b * LIN + i] = s_y[pp * 65 + ff];
    }
}

// ---------------- K6: split-K reduce + bias + lrelu ----------------
__global__ __launch_bounds__(256) void k6_reduce(
    const float* __restrict__ part, const float* __restrict__ a1b,
    const float* __restrict__ v1b, float* __restrict__ h1)
{
    int g = blockIdx.x * 256 + threadIdx.x;   // 512*256
    int n = g & 255;
    float s = (n < 128) ? a1b[n] : v1b[n - 128];
    for (int z = 0; z < KSPLIT; ++z) s += part[(size_t)z * (BS * 256) + g];
    h1[g] = s > 0.f ? s : 0.01f * s;
}

// ---------------- K7: layer2 + heads + log_softmax/entropy/value ----------------
__global__ __launch_bounds__(128) void k7_heads(
    const float* __restrict__ h1, const int* __restrict__ action,
    const float* __restrict__ a2, const float* __restrict__ a2b,
    const float* __restrict__ a3, const float* __restrict__ a3b,
    const float* __restrict__ v2, const float* __restrict__ v2b,
    const float* __restrict__ v3, const float* __restrict__ v3b,
    float* __restrict__ out)
{
    int b = blockIdx.x, tid = threadIdx.x;
    __shared__ float h1a[128], h1v[128], h2a[128], red[128];
    __shared__ float lg[5];
    h1a[tid] = h1[b * 256 + tid];
    h1v[tid] = h1[b * 256 + 128 + tid];
    __syncthreads();
    float sa = a2b[tid], sv = v2b[tid];
    for (int k = 0; k < 128; ++k) {
        sa += h1a[k] * a2[k * 128 + tid];
        sv += h1v[k] * v2[k * 128 + tid];
    }
    sa = sa > 0.f ? sa : 0.01f * sa;
    sv = sv > 0.f ? sv : 0.01f * sv;
    h2a[tid] = sa;
    red[tid] = sv * v3[tid];
    __syncthreads();
    for (int s = 64; s > 0; s >>= 1) {
        if (tid < s) red[tid] += red[tid + s];
        __syncthreads();
    }
    if (tid < 5) {
        float l = a3b[tid];
        for (int k = 0; k < 128; ++k) l += h2a[k] * a3[k * 5 + tid];
        lg[tid] = l;
    }
    __syncthreads();
    if (tid == 0) {
        float m = lg[0];
        for (int j2 = 1; j2 < 5; ++j2) m = fmaxf(m, lg[j2]);
        float se = 0.f;
        for (int j2 = 0; j2 < 5; ++j2) se += expf(lg[j2] - m);
        float lse = m + logf(se);
        int act = action[b];
        float ent = 0.f;
        for (int j2 = 0; j2 < 5; ++j2) {
            float lp = lg[j2] - lse;
            ent -= expf(lp) * lp;
        }
        out[b]        = lg[act] - lse;     // action_logprobs
        out[512 + b]  = red[0] + v3b[0];   // state_value
        out[1024 + b] = ent;               // entropy
    }
}

// ---------------- launch ----------------
extern "C" void kernel_launch(void* const* d_in, const int* in_sizes, int n_in,
                              void* d_out, int out_size, void* d_ws, size_t ws_size,
                              hipStream_t stream)
{
    const int*   state  = (const int*)d_in[0];
    const int*   action = (const int*)d_in[1];
    const float* temb   = (const float*)d_in[2];
    const float* sprite = (const float*)d_in[3];
    const float* conv_w = (const float*)d_in[4];
    const float* conv_b = (const float*)d_in[5];
    const float* Wk     = (const float*)d_in[6];
    const float* bk     = (const float*)d_in[7];
    const float* Wks    = (const float*)d_in[8];
    const float* Wv     = (const float*)d_in[10];
    const float* bv     = (const float*)d_in[11];
    const float* Wvs    = (const float*)d_in[12];
    const float* a1     = (const float*)d_in[14];
    const float* a1b    = (const float*)d_in[15];
    const float* a2     = (const float*)d_in[16];
    const float* a2b    = (const float*)d_in[17];
    const float* a3     = (const float*)d_in[18];
    const float* a3b    = (const float*)d_in[19];
    const float* v1     = (const float*)d_in[20];
    const float* v1b    = (const float*)d_in[21];
    const float* v2     = (const float*)d_in[22];
    const float* v2b    = (const float*)d_in[23];
    const float* v3     = (const float*)d_in[24];
    const float* v3b    = (const float*)d_in[25];
    (void)in_sizes; (void)n_in; (void)out_size; (void)ws_size;

    float* ws  = (float*)d_ws;
    float* XK  = ws + OFF_XK;
    float* XV  = ws + OFF_XV;
    float* P   = ws + OFF_P;
    float* C0  = ws + OFF_C0;
    int*   FL  = (int*)(ws + OFF_FL);
    float* W2  = ws + OFF_W2;
    float* RD  = ws + OFF_RD;
    float* DT  = ws + OFF_DT;
    float* V   = ws + OFF_V;
    float* VW  = ws + OFF_VW;
    float* Y   = ws + OFF_Y;
    float* PART= ws + OFF_PART;
    float* H1  = ws + OFF_H1;
    float* out = (float*)d_out;

    k0_prep<<<769, 256, 0, stream>>>(conv_w, sprite, bk, W2, C0, FL);
    k1_temb<<<NBS, 256, 0, stream>>>(temb, Wks, Wvs, XK, XV);

    // P = sprite @ Wk^T        (25 x 768, K=256, NT)
    gemm_f32<64,64,1,0,0><<<dim3(1,12,1),256,0,stream>>>(sprite,256, Wk,256, nullptr, P,768, 0, 25,768,256, 256);
    // rowdot = sprite @ W2     (25 x 768, K=256, NN)
    gemm_f32<64,64,0,0,0><<<dim3(1,12,1),256,0,stream>>>(sprite,256, W2,768, nullptr, RD,768, 0, 25,768,256, 256);
    // dot_table = xbar_k @ P^T + c0   (1536 x 25, K=768, NT)
    gemm_f32<32,64,1,1,0><<<dim3(48,1,1),256,0,stream>>>(XK,768, P,768, C0, DT,25, 0, NBS,25,768, 768);
    // v = xbar_v @ Wv + bv     (1536 x 256, K=768, NN)
    gemm_f32<32,64,0,1,0><<<dim3(48,4,1),256,0,stream>>>(XV,768, Wv,256, bv, V,256, 0, NBS,256,768, 768);
    // vW = v @ W2              (1536 x 768, K=256, NN)
    gemm_f32<64,64,0,0,0><<<dim3(24,12,1),256,0,stream>>>(V,256, W2,768, nullptr, VW,768, 0, NBS,768,256, 256);

    k4_y<<<BS, 256, 0, stream>>>(state, DT, FL, VW, RD, conv_b, Y);

    // split-K layer-1 GEMMs: partial[z][m][0:128]=actor, [128:256]=value
    gemm_f32<64,64,0,0,0><<<dim3(8,2,KSPLIT),256,0,stream>>>(Y,LIN, a1,128, nullptr, PART,      256, (size_t)BS*256, BS,128,LIN, KCH);
    gemm_f32<64,64,0,0,0><<<dim3(8,2,KSPLIT),256,0,stream>>>(Y,LIN, v1,128, nullptr, PART+128,  256, (size_t)BS*256, BS,128,LIN, KCH);
    k6_reduce<<<512, 256, 0, stream>>>(PART, a1b, v1b, H1);

    k7_heads<<<BS, 128, 0, stream>>>(H1, action, a2, a2b, a3, a3b, v2, v2b, v3, v3b, out);
}

// Round 2
// 161.236 us; speedup vs baseline: 1.7192x; 1.7192x over previous
//
#include <hip/hip_runtime.h>
#include <hip/hip_bf16.h>
#include <math.h>

// ---------------- problem constants ----------------
constexpr int BS   = 512;
constexpr int DM   = 768;
constexpr int NBS  = 1536;   // BS * NSENT
constexpr int NPOS = 300;    // HIST*H*W
constexpr int LIN  = 5184;   // FM * 9 * 9
constexpr int KSPLIT = 27, KCH = 192;   // 27*192 = 5184

typedef __attribute__((ext_vector_type(8))) short bf16x8;
typedef __attribute__((ext_vector_type(4))) float f32x4;

static __device__ __forceinline__ short f2bf(float f) {
    unsigned u = __float_as_uint(f);
    unsigned r = (u + 0x7FFFu + ((u >> 16) & 1u)) >> 16;
    return (short)r;
}

// ---------------- workspace layout (float offsets) ----------------
constexpr size_t OFF_P    = 0;          // 25*768 fp32
constexpr size_t OFF_C0   = 19200;      // 64
constexpr size_t OFF_FL   = 19264;      // 64 (int)
constexpr size_t OFF_RD   = 19328;      // 25*768 fp32
constexpr size_t OFF_DT   = 38528;      // 1536*25 fp32
constexpr size_t OFF_W2T  = 76928;      // bf16 [768][256] -> 98304 floats
constexpr size_t OFF_WVT  = 175232;     // bf16 [256][768] -> 98304
constexpr size_t OFF_AB   = 273536;     // bf16 [256][5184] -> 663552
constexpr size_t OFF_XVH  = 937088;     // bf16 [1536][768] -> 589824
constexpr size_t OFF_VH   = 1526912;    // bf16 [1536][256] -> 196608
constexpr size_t OFF_VW   = 1723520;    // fp32 [1536][768]
constexpr size_t OFF_YH   = 2903168;    // bf16 [512][5184] -> 1327104
constexpr size_t OFF_PART = 4230272;    // fp32 [27][512][256]

// ---------------- kA: all prep (transposes to bf16 K-major, P, RD, C0, flags) ----
__global__ __launch_bounds__(256) void kA_prep(
    const float* __restrict__ conv_w, const float* __restrict__ sprite,
    const float* __restrict__ bk, const float* __restrict__ Wk,
    const float* __restrict__ Wv, const float* __restrict__ a1,
    const float* __restrict__ v1,
    short* __restrict__ W2T, short* __restrict__ WVT, short* __restrict__ AB,
    float* __restrict__ P, float* __restrict__ RD,
    float* __restrict__ C0, int* __restrict__ FL)
{
    __shared__ float tile[64][65];
    int bx = blockIdx.x, tid = threadIdx.x;
    if (bx < 48) {
        // W2T[n=(t4*3+j)*64+f][c] = conv_w[t4][j*256+c][f]   (bf16)
        int p = bx >> 2, cq = bx & 3;
        int t4 = p / 3, j = p - t4 * 3;
        int c0 = cq * 64;
        #pragma unroll
        for (int it = 0; it < 16; ++it) {
            int idx = it * 256 + tid; int ci = idx >> 6, f = idx & 63;
            tile[ci][f] = conv_w[(size_t)(t4 * 768 + j * 256 + c0 + ci) * 64 + f];
        }
        __syncthreads();
        #pragma unroll
        for (int it = 0; it < 16; ++it) {
            int idx = it * 256 + tid; int f = idx >> 6, ci = idx & 63;
            W2T[(size_t)((t4 * 3 + j) * 64 + f) * 256 + c0 + ci] = f2bf(tile[ci][f]);
        }
    } else if (bx < 96) {
        // WVT[n][k] = Wv[k][n]   (Wv is 768x256)
        int id = bx - 48; int kt = id % 12, nt = id / 12;
        #pragma unroll
        for (int it = 0; it < 16; ++it) {
            int idx = it * 256 + tid; int ki = idx >> 6, ni = idx & 63;
            tile[ki][ni] = Wv[(size_t)(kt * 64 + ki) * 256 + nt * 64 + ni];
        }
        __syncthreads();
        #pragma unroll
        for (int it = 0; it < 16; ++it) {
            int idx = it * 256 + tid; int ni = idx >> 6, ki = idx & 63;
            WVT[(size_t)(nt * 64 + ni) * 768 + kt * 64 + ki] = f2bf(tile[ki][ni]);
        }
    } else if (bx < 420) {
        // AB[n][k]: n<128 -> a1 col n ; n>=128 -> v1 col n-128  (both 5184x128)
        int id = bx - 96; int kt = id % 81, nt = id / 81;
        const float* src = (nt < 2) ? a1 : v1;
        int col0 = (nt & 1) * 64;
        #pragma unroll
        for (int it = 0; it < 16; ++it) {
            int idx = it * 256 + tid; int ki = idx >> 6, ni = idx & 63;
            tile[ki][ni] = src[(size_t)(kt * 64 + ki) * 128 + col0 + ni];
        }
        __syncthreads();
        #pragma unroll
        for (int it = 0; it < 16; ++it) {
            int idx = it * 256 + tid; int ni = idx >> 6, ki = idx & 63;
            AB[(size_t)(nt * 64 + ni) * 5184 + kt * 64 + ki] = f2bf(tile[ki][ni]);
        }
    } else if (bx < 495) {
        // P[o][d] = sum_c sprite[o][c]*Wk[d][c]
        int g = (bx - 420) * 256 + tid; int o = g / 768, d = g - o * 768;
        const float* sp = sprite + o * 256;
        const float* wr = Wk + (size_t)d * 256;
        float s = 0.f;
        for (int c = 0; c < 256; ++c) s += sp[c] * wr[c];
        P[g] = s;
    } else if (bx < 570) {
        // RD[o][n] = sum_e sprite[o][e]*conv_w[t4][j*256+e][f],  n=(t4*3+j)*64+f
        int g = (bx - 495) * 256 + tid; int o = g / 768, n = g - o * 768;
        int tap = n >> 6, f = n & 63; int t4 = tap / 3, j = tap - t4 * 3;
        const float* sp = sprite + o * 256;
        float s = 0.f;
        for (int e = 0; e < 256; ++e)
            s += sp[e] * conv_w[(size_t)(t4 * 768 + j * 256 + e) * 64 + f];
        RD[g] = s;
    } else {
        if (tid < 25) {
            float s = 0.f, cc = 0.f;
            for (int c = 0; c < 256; ++c) {
                float e = sprite[tid * 256 + c];
                s += e; cc += e * bk[c];
            }
            FL[tid] = (s != 0.0f) ? 1 : 0;
            C0[tid] = cc;
        }
    }
}

// ---------------- kB: token softmax sums + DT + XVh ----------------
__global__ __launch_bounds__(256) void kB_temb(
    const float* __restrict__ temb, const float* __restrict__ Wks,
    const float* __restrict__ Wvs, const float* __restrict__ P,
    const float* __restrict__ C0,
    short* __restrict__ XVH, float* __restrict__ DT)
{
    __shared__ float sWk[DM], sWv[DM];
    __shared__ float chunk[12 * DM];
    __shared__ float sk[12], sv[12];
    int tid = threadIdx.x;
    int bs  = blockIdx.x;
    const float* src = temb + (size_t)bs * 36 * DM;
    for (int i = tid; i < DM; i += 256) { sWk[i] = Wks[i]; sWv[i] = Wvs[i]; }

    float mk = -INFINITY, mv = -INFINITY, Zk = 0.f, Zv = 0.f;
    float ak[3] = {0.f, 0.f, 0.f}, av[3] = {0.f, 0.f, 0.f};
    int lane = tid & 63, wv = tid >> 6;

    for (int c = 0; c < 3; ++c) {
        __syncthreads();
        const float4* s4 = (const float4*)(src + (size_t)c * 12 * DM);
        float4* d4 = (float4*)chunk;
        #pragma unroll
        for (int i = 0; i < 9; ++i) d4[tid + i * 256] = s4[tid + i * 256];
        __syncthreads();
        #pragma unroll
        for (int tt = 0; tt < 3; ++tt) {
            int t = wv * 3 + tt;
            const float* row = chunk + t * DM;
            float pk = 0.f, pv = 0.f;
            for (int d = lane; d < DM; d += 64) {
                float x = row[d];
                pk += x * sWk[d]; pv += x * sWv[d];
            }
            #pragma unroll
            for (int off = 32; off; off >>= 1) {
                pk += __shfl_down(pk, off);
                pv += __shfl_down(pv, off);
            }
            if (lane == 0) { sk[t] = pk; sv[t] = pv; }
        }
        __syncthreads();
        float cmk = sk[0], cmv = sv[0];
        #pragma unroll
        for (int t = 1; t < 12; ++t) { cmk = fmaxf(cmk, sk[t]); cmv = fmaxf(cmv, sv[t]); }
        float nmk = fmaxf(mk, cmk), nmv = fmaxf(mv, cmv);
        float rk = expf(mk - nmk), rv = expf(mv - nmv);
        mk = nmk; mv = nmv;
        float wk[12], wvv[12], swk = 0.f, swv = 0.f;
        #pragma unroll
        for (int t = 0; t < 12; ++t) {
            wk[t]  = expf(sk[t] - nmk); swk += wk[t];
            wvv[t] = expf(sv[t] - nmv); swv += wvv[t];
        }
        Zk = Zk * rk + swk; Zv = Zv * rv + swv;
        float sxk[3] = {0.f, 0.f, 0.f}, sxv[3] = {0.f, 0.f, 0.f};
        #pragma unroll
        for (int t = 0; t < 12; ++t) {
            #pragma unroll
            for (int j = 0; j < 3; ++j) {
                float x = chunk[t * DM + tid + j * 256];
                sxk[j] += wk[t] * x; sxv[j] += wvv[t] * x;
            }
        }
        #pragma unroll
        for (int j = 0; j < 3; ++j) {
            ak[j] = ak[j] * rk + sxk[j];
            av[j] = av[j] * rv + sxv[j];
        }
    }
    float izk = 1.f / Zk, izv = 1.f / Zv;
    #pragma unroll
    for (int j = 0; j < 3; ++j)
        XVH[(size_t)bs * DM + tid + j * 256] = f2bf(av[j] * izv);

    __syncthreads();                // all chunk reads done
    #pragma unroll
    for (int j = 0; j < 3; ++j) chunk[tid + j * 256] = ak[j] * izk;
    __syncthreads();
    // DT[bs][o] = xbar_k . P[o] + C0[o]
    for (int o = wv; o < 25; o += 4) {
        const float* pr = P + o * 768;
        float s = 0.f;
        for (int d = lane; d < 768; d += 64) s += chunk[d] * pr[d];
        #pragma unroll
        for (int off = 32; off; off >>= 1) s += __shfl_down(s, off);
        if (lane == 0) DT[bs * 25 + o] = s + C0[o];
    }
}

// ---------------- MFMA bf16 GEMM: A[M][K] row-major, B[N][K] K-major ----------
// BM=BN=64, BK=32. M%64==0, N%64==0, klen%32==0 required.
template<int BIAS, int OUTBF>
__global__ __launch_bounds__(256) void gemm_mfma(
    const short* __restrict__ A, const short* __restrict__ B,
    const float* __restrict__ bias, void* __restrict__ Cout,
    int K, int ldc, int klen, size_t czstride)
{
    __shared__ short As[64][40];
    __shared__ short Bs[64][40];
    int tid = threadIdx.x;
    int bm = blockIdx.x * 64, bn = blockIdx.y * 64;
    int wid = tid >> 6, lane = tid & 63;
    int wm = (wid >> 1) * 32, wn = (wid & 1) * 32;
    int l15 = lane & 15, lg = lane >> 4;

    f32x4 zero = {0.f, 0.f, 0.f, 0.f};
    f32x4 acc00 = zero, acc01 = zero, acc10 = zero, acc11 = zero;

    int srow = tid >> 2, kch = (tid & 3) * 8;
    const short* Ap = A + (size_t)(bm + srow) * K + kch + (size_t)blockIdx.z * klen;
    const short* Bp = B + (size_t)(bn + srow) * K + kch + (size_t)blockIdx.z * klen;

    for (int kt = 0; kt < klen; kt += 32) {
        bf16x8 aval = *(const bf16x8*)(Ap + kt);
        bf16x8 bval = *(const bf16x8*)(Bp + kt);
        *(bf16x8*)&As[srow][kch] = aval;
        *(bf16x8*)&Bs[srow][kch] = bval;
        __syncthreads();
        bf16x8 af0 = *(const bf16x8*)&As[wm + l15][lg * 8];
        bf16x8 af1 = *(const bf16x8*)&As[wm + 16 + l15][lg * 8];
        bf16x8 bg0 = *(const bf16x8*)&Bs[wn + l15][lg * 8];
        bf16x8 bg1 = *(const bf16x8*)&Bs[wn + 16 + l15][lg * 8];
        acc00 = __builtin_amdgcn_mfma_f32_16x16x32_bf16(af0, bg0, acc00, 0, 0, 0);
        acc01 = __builtin_amdgcn_mfma_f32_16x16x32_bf16(af0, bg1, acc01, 0, 0, 0);
        acc10 = __builtin_amdgcn_mfma_f32_16x16x32_bf16(af1, bg0, acc10, 0, 0, 0);
        acc11 = __builtin_amdgcn_mfma_f32_16x16x32_bf16(af1, bg1, acc11, 0, 0, 0);
        __syncthreads();
    }

    float* Cf = (float*)Cout + (size_t)blockIdx.z * czstride;
    short* Ch = (short*)Cout;
    #pragma unroll
    for (int i = 0; i < 2; ++i) {
        f32x4 arow0 = (i == 0) ? acc00 : acc10;
        f32x4 arow1 = (i == 0) ? acc01 : acc11;
        #pragma unroll
        for (int j = 0; j < 2; ++j) {
            f32x4 a = (j == 0) ? arow0 : arow1;
            int col = bn + wn + j * 16 + l15;
            float bb = BIAS ? bias[col] : 0.f;
            #pragma unroll
            for (int r = 0; r < 4; ++r) {
                int row = bm + wm + i * 16 + lg * 4 + r;
                float v = a[r] + bb;
                if (OUTBF) Ch[(size_t)row * ldc + col] = f2bf(v);
                else       Cf[(size_t)row * ldc + col] = v;
            }
        }
    }
}

// ---------------- k4: wts + factored conv + transpose-flatten + lrelu -> Yh --
__global__ __launch_bounds__(256) void k4_y(
    const int* __restrict__ state, const float* __restrict__ dt,
    const int* __restrict__ flags, const float* __restrict__ vW,
    const float* __restrict__ rowdot, const float* __restrict__ conv_b,
    short* __restrict__ y)
{
    int b = blockIdx.x, tid = threadIdx.x;
    __shared__ float s_vW[3 * 768];
    __shared__ float s_w[3][NPOS + 4];
    __shared__ int   s_avt[NPOS + 4];
    __shared__ float s_y[81 * 65];

    const float4* vs = (const float4*)(vW + (size_t)b * 3 * 768);
    float4* vd = (float4*)s_vW;
    for (int i = tid; i < 576; i += 256) vd[i] = vs[i];

    for (int code = tid; code < NPOS; code += 256) {
        const int* st = state + ((size_t)b * NPOS + code) * 4;
        int o0 = st[0], o1 = st[1], o2 = st[2], avi = st[3];
        int cnt = flags[o0] + flags[o1] + flags[o2];
        s_avt[code] = avi;
        float w0 = 0.f, w1 = 0.f, w2 = 0.f;
        if (cnt > 0) {
            const float* d0 = dt + (size_t)b * 75;
            float inv = 1.0f / (16.0f * (float)cnt);
            float q0 = (d0[o0]      + d0[o1]      + d0[o2])      * inv;
            float q1 = (d0[25 + o0] + d0[25 + o1] + d0[25 + o2]) * inv;
            float q2 = (d0[50 + o0] + d0[50 + o1] + d0[50 + o2]) * inv;
            float m = fmaxf(q0, fmaxf(q1, q2));
            float e0 = expf(q0 - m), e1 = expf(q1 - m), e2 = expf(q2 - m);
            float is = 1.0f / (6.0f * (e0 + e1 + e2));
            w0 = e0 * is; w1 = e1 * is; w2 = e2 * is;
        }
        s_w[0][code] = w0; s_w[1][code] = w1; s_w[2][code] = w2;
    }
    __syncthreads();

    int f = tid & 63;
    float cb = conv_b[f];
    for (int p = tid >> 6; p < 81; p += 4) {
        int oh = p / 9, ow = p - oh * 9;
        float acc = cb;
        #pragma unroll
        for (int kh = 0; kh < 2; ++kh)
        #pragma unroll
        for (int kw = 0; kw < 2; ++kw) {
            int bc = 3 * ((oh + kh) * 10 + (ow + kw));
            int tbase = ((kh * 2 + kw) * 3) * 64 + f;
            #pragma unroll
            for (int j = 0; j < 3; ++j) {
                int code = bc + j;
                int tf = tbase + j * 64;
                acc += s_w[0][code] * s_vW[tf]
                     + s_w[1][code] * s_vW[768 + tf]
                     + s_w[2][code] * s_vW[2 * 768 + tf];
                acc += 0.5f * rowdot[(size_t)s_avt[code] * 768 + tf];
            }
        }
        acc = acc > 0.f ? acc : 0.01f * acc;
        s_y[p * 65 + f] = acc;
    }
    __syncthreads();
    for (int i = tid; i < LIN; i += 256) {
        int ff = i / 81, pp = i - ff * 81;
        y[(size_t)b * LIN + i] = f2bf(s_y[pp * 65 + ff]);
    }
}

// ---------------- k7: split-K reduce + layer2 + heads ----------------
__global__ __launch_bounds__(128) void k7_heads(
    const float* __restrict__ PART, const float* __restrict__ a1b,
    const float* __restrict__ v1b, const int* __restrict__ action,
    const float* __restrict__ a2, const float* __restrict__ a2b,
    const float* __restrict__ a3, const float* __restrict__ a3b,
    const float* __restrict__ v2, const float* __restrict__ v2b,
    const float* __restrict__ v3, const float* __restrict__ v3b,
    float* __restrict__ out)
{
    int b = blockIdx.x, tid = threadIdx.x;
    __shared__ float h1a[128], h1v[128], h2a[128], red[128];
    __shared__ float lg[5];
    float sa0 = a1b[tid], sv0 = v1b[tid];
    const float* pb = PART + (size_t)b * 256;
    for (int z = 0; z < KSPLIT; ++z) {
        sa0 += pb[(size_t)z * (BS * 256) + tid];
        sv0 += pb[(size_t)z * (BS * 256) + 128 + tid];
    }
    h1a[tid] = sa0 > 0.f ? sa0 : 0.01f * sa0;
    h1v[tid] = sv0 > 0.f ? sv0 : 0.01f * sv0;
    __syncthreads();
    float sa = a2b[tid], sv = v2b[tid];
    for (int k = 0; k < 128; ++k) {
        sa += h1a[k] * a2[k * 128 + tid];
        sv += h1v[k] * v2[k * 128 + tid];
    }
    sa = sa > 0.f ? sa : 0.01f * sa;
    sv = sv > 0.f ? sv : 0.01f * sv;
    h2a[tid] = sa;
    red[tid] = sv * v3[tid];
    __syncthreads();
    for (int s = 64; s > 0; s >>= 1) {
        if (tid < s) red[tid] += red[tid + s];
        __syncthreads();
    }
    if (tid < 5) {
        float l = a3b[tid];
        for (int k = 0; k < 128; ++k) l += h2a[k] * a3[k * 5 + tid];
        lg[tid] = l;
    }
    __syncthreads();
    if (tid == 0) {
        float m = lg[0];
        for (int j2 = 1; j2 < 5; ++j2) m = fmaxf(m, lg[j2]);
        float se = 0.f;
        for (int j2 = 0; j2 < 5; ++j2) se += expf(lg[j2] - m);
        float lse = m + logf(se);
        int act = action[b];
        float ent = 0.f;
        for (int j2 = 0; j2 < 5; ++j2) {
            float lp = lg[j2] - lse;
            ent -= expf(lp) * lp;
        }
        out[b]        = lg[act] - lse;
        out[512 + b]  = red[0] + v3b[0];
        out[1024 + b] = ent;
    }
}

// ---------------- launch ----------------
extern "C" void kernel_launch(void* const* d_in, const int* in_sizes, int n_in,
                              void* d_out, int out_size, void* d_ws, size_t ws_size,
                              hipStream_t stream)
{
    const int*   state  = (const int*)d_in[0];
    const int*   action = (const int*)d_in[1];
    const float* temb   = (const float*)d_in[2];
    const float* sprite = (const float*)d_in[3];
    const float* conv_w = (const float*)d_in[4];
    const float* conv_b = (const float*)d_in[5];
    const float* Wk     = (const float*)d_in[6];
    const float* bk     = (const float*)d_in[7];
    const float* Wks    = (const float*)d_in[8];
    const float* Wv     = (const float*)d_in[10];
    const float* bv     = (const float*)d_in[11];
    const float* Wvs    = (const float*)d_in[12];
    const float* a1     = (const float*)d_in[14];
    const float* a1b    = (const float*)d_in[15];
    const float* a2     = (const float*)d_in[16];
    const float* a2b    = (const float*)d_in[17];
    const float* a3     = (const float*)d_in[18];
    const float* a3b    = (const float*)d_in[19];
    const float* v1     = (const float*)d_in[20];
    const float* v1b    = (const float*)d_in[21];
    const float* v2     = (const float*)d_in[22];
    const float* v2b    = (const float*)d_in[23];
    const float* v3     = (const float*)d_in[24];
    const float* v3b    = (const float*)d_in[25];
    (void)in_sizes; (void)n_in; (void)out_size; (void)ws_size;

    float* ws  = (float*)d_ws;
    float* P   = ws + OFF_P;
    float* C0  = ws + OFF_C0;
    int*   FL  = (int*)(ws + OFF_FL);
    float* RD  = ws + OFF_RD;
    float* DT  = ws + OFF_DT;
    short* W2T = (short*)(ws + OFF_W2T);
    short* WVT = (short*)(ws + OFF_WVT);
    short* AB  = (short*)(ws + OFF_AB);
    short* XVH = (short*)(ws + OFF_XVH);
    short* VH  = (short*)(ws + OFF_VH);
    float* VW  = ws + OFF_VW;
    short* YH  = (short*)(ws + OFF_YH);
    float* PART= ws + OFF_PART;
    float* out = (float*)d_out;

    kA_prep<<<571, 256, 0, stream>>>(conv_w, sprite, bk, Wk, Wv, a1, v1,
                                     W2T, WVT, AB, P, RD, C0, FL);
    kB_temb<<<NBS, 256, 0, stream>>>(temb, Wks, Wvs, P, C0, XVH, DT);

    // Vh = XVh @ Wv + bv   (1536 x 256, K=768) -> bf16
    gemm_mfma<1,1><<<dim3(24,4,1),256,0,stream>>>(XVH, WVT, bv, VH, 768, 256, 768, 0);
    // VW = Vh @ W2         (1536 x 768, K=256) -> fp32
    gemm_mfma<0,0><<<dim3(24,12,1),256,0,stream>>>(VH, W2T, nullptr, VW, 256, 768, 256, 0);

    k4_y<<<BS, 256, 0, stream>>>(state, DT, FL, VW, RD, conv_b, YH);

    // PART[z] = Yh @ [a1||v1] slice  (512 x 256, K split 27x192) -> fp32
    gemm_mfma<0,0><<<dim3(8,4,KSPLIT),256,0,stream>>>(YH, AB, nullptr, PART, 5184, 256, KCH, (size_t)BS*256);

    k7_heads<<<BS, 128, 0, stream>>>(PART, a1b, v1b, action, a2, a2b, a3, a3b,
                                     v2, v2b, v3, v3b, out);
}

// Round 3
// 136.795 us; speedup vs baseline: 2.0263x; 1.1787x over previous
//
#include <hip/hip_runtime.h>
#include <hip/hip_bf16.h>
#include <math.h>

// ---------------- problem constants ----------------
constexpr int BS   = 512;
constexpr int DM   = 768;
constexpr int NBS  = 1536;   // BS * NSENT
constexpr int NPOS = 300;    // HIST*H*W
constexpr int LIN  = 5184;   // FM * 9 * 9
constexpr int KSPLIT = 27, KCH = 192;   // 27*192 = 5184

typedef __attribute__((ext_vector_type(8))) short bf16x8;
typedef __attribute__((ext_vector_type(4))) short s16x4;
typedef __attribute__((ext_vector_type(4))) float f32x4;

static __device__ __forceinline__ short f2bf(float f) {
    unsigned u = __float_as_uint(f);
    unsigned r = (u + 0x7FFFu + ((u >> 16) & 1u)) >> 16;
    return (short)r;
}

// ---------------- workspace layout (float offsets) ----------------
constexpr size_t OFF_P    = 0;          // 25*768 fp32
constexpr size_t OFF_C0   = 19200;      // 64
constexpr size_t OFF_FL   = 19264;      // 64 (int)
constexpr size_t OFF_RD   = 19328;      // 26*768 fp32 (rows 0..24 rowdot, row 25 = bv@W2)
constexpr size_t OFF_DT   = 39296;      // 1536*25 fp32
constexpr size_t OFF_W2T  = 77696;      // bf16 [768][256] -> 98304 floats
constexpr size_t OFF_WVH  = 176000;     // bf16 [768][256] -> 98304
constexpr size_t OFF_WCT  = 274304;     // bf16 [768][768] -> 294912
constexpr size_t OFF_AB   = 569216;     // bf16 [256][5184] -> 663552
constexpr size_t OFF_SK   = 1232768;    // 55296 fp32
constexpr size_t OFF_SV   = 1288064;    // 55296 fp32
constexpr size_t OFF_XVH  = 1343360;    // bf16 [1536][768] -> 589824
constexpr size_t OFF_VW   = 1933184;    // fp32 [1536][768]
constexpr size_t OFF_YH   = 3112832;    // bf16 [512][5184] -> 1327104
constexpr size_t OFF_PART = 4439936;    // fp32 [27][512][256] ; end = 7978880 floats (~31.9MB)

// ---------------- kA: prep (bf16 repacks, P, RD+bvW2, C0, flags) ----------------
__global__ __launch_bounds__(256) void kA_prep(
    const float* __restrict__ conv_w, const float* __restrict__ sprite,
    const float* __restrict__ bk, const float* __restrict__ Wk,
    const float* __restrict__ Wv, const float* __restrict__ bv,
    const float* __restrict__ a1, const float* __restrict__ v1,
    short* __restrict__ W2T, short* __restrict__ WVH, short* __restrict__ AB,
    float* __restrict__ P, float* __restrict__ RD,
    float* __restrict__ C0, int* __restrict__ FL)
{
    __shared__ float tile[64][65];
    int bx = blockIdx.x, tid = threadIdx.x;
    if (bx < 48) {
        // W2T[n=(t4*3+j)*64+f][c] = conv_w[t4][j*256+c][f]   (bf16, K-major over c)
        int p = bx >> 2, cq = bx & 3;
        int t4 = p / 3, j = p - t4 * 3;
        int c0 = cq * 64;
        #pragma unroll
        for (int it = 0; it < 16; ++it) {
            int idx = it * 256 + tid; int ci = idx >> 6, f = idx & 63;
            tile[ci][f] = conv_w[(size_t)(t4 * 768 + j * 256 + c0 + ci) * 64 + f];
        }
        __syncthreads();
        #pragma unroll
        for (int it = 0; it < 16; ++it) {
            int idx = it * 256 + tid; int f = idx >> 6, ci = idx & 63;
            W2T[(size_t)((t4 * 3 + j) * 64 + f) * 256 + c0 + ci] = f2bf(tile[ci][f]);
        }
    } else if (bx < 96) {
        // WVH = bf16(Wv), row-major [768][256]
        int id = bx - 48;
        int base = id * 4096 + tid * 16;
        #pragma unroll
        for (int q = 0; q < 4; ++q) {
            float4 v = *(const float4*)(Wv + base + q * 4);
            s16x4 h = { f2bf(v.x), f2bf(v.y), f2bf(v.z), f2bf(v.w) };
            *(s16x4*)(WVH + base + q * 4) = h;
        }
    } else if (bx < 420) {
        // AB[n][k]: n<128 -> a1 col n ; n>=128 -> v1 col n-128  (both 5184x128)
        int id = bx - 96; int kt = id % 81, nt = id / 81;
        const float* src = (nt < 2) ? a1 : v1;
        int col0 = (nt & 1) * 64;
        #pragma unroll
        for (int it = 0; it < 16; ++it) {
            int idx = it * 256 + tid; int ki = idx >> 6, ni = idx & 63;
            tile[ki][ni] = src[(size_t)(kt * 64 + ki) * 128 + col0 + ni];
        }
        __syncthreads();
        #pragma unroll
        for (int it = 0; it < 16; ++it) {
            int idx = it * 256 + tid; int ni = idx >> 6, ki = idx & 63;
            AB[(size_t)(nt * 64 + ni) * 5184 + kt * 64 + ki] = f2bf(tile[ki][ni]);
        }
    } else if (bx < 495) {
        // P[o][d] = sum_c sprite[o][c]*Wk[d][c]
        int g = (bx - 420) * 256 + tid; int o = g / 768, d = g - o * 768;
        const float* sp = sprite + o * 256;
        const float* wr = Wk + (size_t)d * 256;
        float s = 0.f;
        for (int c = 0; c < 256; ++c) s += sp[c] * wr[c];
        P[g] = s;
    } else if (bx < 573) {
        // RD[o][n]: o<25 rowdot rows (sprite), o==25 -> bv@W2
        int g = (bx - 495) * 256 + tid;  // 0..19967
        int o = g / 768, n = g - o * 768;
        int tap = n >> 6, f = n & 63; int t4 = tap / 3, j = tap - t4 * 3;
        const float* sp = (o < 25) ? (sprite + o * 256) : bv;
        float s = 0.f;
        for (int e = 0; e < 256; ++e)
            s += sp[e] * conv_w[(size_t)(t4 * 768 + j * 256 + e) * 64 + f];
        RD[g] = s;
    } else {
        if (tid < 25) {
            float s = 0.f, cc = 0.f;
            for (int c = 0; c < 256; ++c) {
                float e = sprite[tid * 256 + c];
                s += e; cc += e * bk[c];
            }
            FL[tid] = (s != 0.0f) ? 1 : 0;
            C0[tid] = cc;
        }
    }
}

// ---------------- kB1: token scores (one wave per (b,s,t) row) ----------------
__global__ __launch_bounds__(256) void kB1_scores(
    const float* __restrict__ temb, const float* __restrict__ Wks,
    const float* __restrict__ Wvs, float* __restrict__ SK, float* __restrict__ SV)
{
    int wid = threadIdx.x >> 6, lane = threadIdx.x & 63;
    int r = blockIdx.x * 4 + wid;            // row over 55296
    const float4* row = (const float4*)temb + (size_t)r * 192;
    const float4* k4 = (const float4*)Wks;
    const float4* v4 = (const float4*)Wvs;
    float pk = 0.f, pv = 0.f;
    #pragma unroll
    for (int i = 0; i < 3; ++i) {
        int d4 = lane + 64 * i;
        float4 x = row[d4];
        float4 wk = k4[d4], wv = v4[d4];
        pk += x.x * wk.x + x.y * wk.y + x.z * wk.z + x.w * wk.w;
        pv += x.x * wv.x + x.y * wv.y + x.z * wv.z + x.w * wv.w;
    }
    #pragma unroll
    for (int off = 32; off; off >>= 1) {
        pk += __shfl_down(pk, off);
        pv += __shfl_down(pv, off);
    }
    if (lane == 0) { SK[r] = pk; SV[r] = pv; }
}

// ---------------- kB2: softmax + weighted sums + DT + XVh ----------------
__global__ __launch_bounds__(256) void kB2_sum(
    const float* __restrict__ temb, const float* __restrict__ SK,
    const float* __restrict__ SV, const float* __restrict__ P,
    const float* __restrict__ C0, short* __restrict__ XVH, float* __restrict__ DT)
{
    __shared__ float swk[40], swv[40];
    __shared__ float xk[768], xv[768];
    int tid = threadIdx.x, wid = tid >> 6, lane = tid & 63;
    int bs = blockIdx.x;

    if (wid < 2) {
        const float* S = wid ? SV : SK;
        float s = (lane < 36) ? S[bs * 36 + lane] : -INFINITY;
        float m = s;
        #pragma unroll
        for (int off = 32; off; off >>= 1) m = fmaxf(m, __shfl_xor(m, off));
        float e = (lane < 36) ? expf(s - m) : 0.f;
        float z = e;
        #pragma unroll
        for (int off = 32; off; off >>= 1) z += __shfl_xor(z, off);
        float* dst = wid ? swv : swk;
        if (lane < 36) dst[lane] = e / z;
    }
    __syncthreads();

    int tl[3], dd[3];
    #pragma unroll
    for (int i = 0; i < 3; ++i) { int g = i * 256 + tid; tl[i] = g / 192; dd[i] = g % 192; }
    float4 accK[3], accV[3];
    #pragma unroll
    for (int i = 0; i < 3; ++i) {
        accK[i] = make_float4(0.f, 0.f, 0.f, 0.f);
        accV[i] = make_float4(0.f, 0.f, 0.f, 0.f);
    }
    const float4* row = (const float4*)temb + (size_t)bs * 6912;
    for (int g = 0; g < 9; ++g) {
        #pragma unroll
        for (int i = 0; i < 3; ++i) {
            float4 x = row[g * 768 + i * 256 + tid];
            float wk = swk[4 * g + tl[i]], wv = swv[4 * g + tl[i]];
            accK[i].x += wk * x.x; accK[i].y += wk * x.y;
            accK[i].z += wk * x.z; accK[i].w += wk * x.w;
            accV[i].x += wv * x.x; accV[i].y += wv * x.y;
            accV[i].z += wv * x.z; accV[i].w += wv * x.w;
        }
    }
    // 4-phase race-free reduction into LDS
    #pragma unroll
    for (int p = 0; p < 4; ++p) {
        #pragma unroll
        for (int i = 0; i < 3; ++i) if (tl[i] == p) {
            if (p == 0) {
                *(float4*)&xk[4 * dd[i]] = accK[i];
                *(float4*)&xv[4 * dd[i]] = accV[i];
            } else {
                float4 t0 = *(const float4*)&xk[4 * dd[i]];
                t0.x += accK[i].x; t0.y += accK[i].y; t0.z += accK[i].z; t0.w += accK[i].w;
                *(float4*)&xk[4 * dd[i]] = t0;
                float4 t1 = *(const float4*)&xv[4 * dd[i]];
                t1.x += accV[i].x; t1.y += accV[i].y; t1.z += accV[i].z; t1.w += accV[i].w;
                *(float4*)&xv[4 * dd[i]] = t1;
            }
        }
        __syncthreads();
    }
    if (tid < 192) {
        float4 vv = *(const float4*)&xv[4 * tid];
        s16x4 h = { f2bf(vv.x), f2bf(vv.y), f2bf(vv.z), f2bf(vv.w) };
        *(s16x4*)(XVH + (size_t)bs * 768 + 4 * tid) = h;
    }
    // DT[bs][o] = xbar_k . P[o] + C0[o]
    for (int o = wid; o < 25; o += 4) {
        const float* pr = P + o * 768;
        float s = 0.f;
        #pragma unroll
        for (int j = 0; j < 12; ++j) s += xk[lane + 64 * j] * pr[lane + 64 * j];
        #pragma unroll
        for (int off = 32; off; off >>= 1) s += __shfl_down(s, off);
        if (lane == 0) DT[bs * 25 + o] = s + C0[o];
    }
}

// ---------------- MFMA bf16 GEMM: A[M][K] row-major, B[N][K] K-major ----------
template<int BIAS, int OUTBF>
__global__ __launch_bounds__(256) void gemm_mfma(
    const short* __restrict__ A, const short* __restrict__ B,
    const float* __restrict__ bias, void* __restrict__ Cout,
    int K, int ldc, int klen, size_t czstride)
{
    __shared__ short As[64][40];
    __shared__ short Bs[64][40];
    int tid = threadIdx.x;
    int bm = blockIdx.x * 64, bn = blockIdx.y * 64;
    int wid = tid >> 6, lane = tid & 63;
    int wm = (wid >> 1) * 32, wn = (wid & 1) * 32;
    int l15 = lane & 15, lg = lane >> 4;

    f32x4 zero = {0.f, 0.f, 0.f, 0.f};
    f32x4 acc00 = zero, acc01 = zero, acc10 = zero, acc11 = zero;

    int srow = tid >> 2, kch = (tid & 3) * 8;
    const short* Ap = A + (size_t)(bm + srow) * K + kch + (size_t)blockIdx.z * klen;
    const short* Bp = B + (size_t)(bn + srow) * K + kch + (size_t)blockIdx.z * klen;

    for (int kt = 0; kt < klen; kt += 32) {
        bf16x8 aval = *(const bf16x8*)(Ap + kt);
        bf16x8 bval = *(const bf16x8*)(Bp + kt);
        *(bf16x8*)&As[srow][kch] = aval;
        *(bf16x8*)&Bs[srow][kch] = bval;
        __syncthreads();
        bf16x8 af0 = *(const bf16x8*)&As[wm + l15][lg * 8];
        bf16x8 af1 = *(const bf16x8*)&As[wm + 16 + l15][lg * 8];
        bf16x8 bg0 = *(const bf16x8*)&Bs[wn + l15][lg * 8];
        bf16x8 bg1 = *(const bf16x8*)&Bs[wn + 16 + l15][lg * 8];
        acc00 = __builtin_amdgcn_mfma_f32_16x16x32_bf16(af0, bg0, acc00, 0, 0, 0);
        acc01 = __builtin_amdgcn_mfma_f32_16x16x32_bf16(af0, bg1, acc01, 0, 0, 0);
        acc10 = __builtin_amdgcn_mfma_f32_16x16x32_bf16(af1, bg0, acc10, 0, 0, 0);
        acc11 = __builtin_amdgcn_mfma_f32_16x16x32_bf16(af1, bg1, acc11, 0, 0, 0);
        __syncthreads();
    }

    float* Cf = (float*)Cout + (size_t)blockIdx.z * czstride;
    short* Ch = (short*)Cout;
    #pragma unroll
    for (int i = 0; i < 2; ++i) {
        f32x4 arow0 = (i == 0) ? acc00 : acc10;
        f32x4 arow1 = (i == 0) ? acc01 : acc11;
        #pragma unroll
        for (int j = 0; j < 2; ++j) {
            f32x4 a = (j == 0) ? arow0 : arow1;
            int col = bn + wn + j * 16 + l15;
            float bb = BIAS ? bias[col] : 0.f;
            #pragma unroll
            for (int r = 0; r < 4; ++r) {
                int row = bm + wm + i * 16 + lg * 4 + r;
                float v = a[r] + bb;
                if (OUTBF) Ch[(size_t)row * ldc + col] = f2bf(v);
                else       Cf[(size_t)row * ldc + col] = v;
            }
        }
    }
}

// ---------------- k4: wts + factored conv + transpose-flatten + lrelu -> Yh --
__global__ __launch_bounds__(256) void k4_y(
    const int* __restrict__ state, const float* __restrict__ dt,
    const int* __restrict__ flags, const float* __restrict__ vW,
    const float* __restrict__ rowdot, const float* __restrict__ conv_b,
    short* __restrict__ y)
{
    int b = blockIdx.x, tid = threadIdx.x;
    __shared__ float s_vW[3 * 768];
    __shared__ float s_w[3][NPOS + 4];
    __shared__ int   s_avt[NPOS + 4];
    __shared__ float s_y[81 * 65];

    const float4* vs = (const float4*)(vW + (size_t)b * 3 * 768);
    float4* vd = (float4*)s_vW;
    for (int i = tid; i < 576; i += 256) vd[i] = vs[i];

    for (int code = tid; code < NPOS; code += 256) {
        const int* st = state + ((size_t)b * NPOS + code) * 4;
        int o0 = st[0], o1 = st[1], o2 = st[2], avi = st[3];
        int cnt = flags[o0] + flags[o1] + flags[o2];
        s_avt[code] = avi;
        float w0 = 0.f, w1 = 0.f, w2 = 0.f;
        if (cnt > 0) {
            const float* d0 = dt + (size_t)b * 75;
            float inv = 1.0f / (16.0f * (float)cnt);
            float q0 = (d0[o0]      + d0[o1]      + d0[o2])      * inv;
            float q1 = (d0[25 + o0] + d0[25 + o1] + d0[25 + o2]) * inv;
            float q2 = (d0[50 + o0] + d0[50 + o1] + d0[50 + o2]) * inv;
            float m = fmaxf(q0, fmaxf(q1, q2));
            float e0 = expf(q0 - m), e1 = expf(q1 - m), e2 = expf(q2 - m);
            float is = 1.0f / (6.0f * (e0 + e1 + e2));
            w0 = e0 * is; w1 = e1 * is; w2 = e2 * is;
        }
        s_w[0][code] = w0; s_w[1][code] = w1; s_w[2][code] = w2;
    }
    __syncthreads();

    int f = tid & 63;
    float cb = conv_b[f];
    for (int p = tid >> 6; p < 81; p += 4) {
        int oh = p / 9, ow = p - oh * 9;
        float acc = cb;
        #pragma unroll
        for (int kh = 0; kh < 2; ++kh)
        #pragma unroll
        for (int kw = 0; kw < 2; ++kw) {
            int bc = 3 * ((oh + kh) * 10 + (ow + kw));
            int tbase = ((kh * 2 + kw) * 3) * 64 + f;
            #pragma unroll
            for (int j = 0; j < 3; ++j) {
                int code = bc + j;
                int tf = tbase + j * 64;
                acc += s_w[0][code] * s_vW[tf]
                     + s_w[1][code] * s_vW[768 + tf]
                     + s_w[2][code] * s_vW[2 * 768 + tf];
                acc += 0.5f * rowdot[(size_t)s_avt[code] * 768 + tf];
            }
        }
        acc = acc > 0.f ? acc : 0.01f * acc;
        s_y[p * 65 + f] = acc;
    }
    __syncthreads();
    for (int i = tid; i < LIN; i += 256) {
        int ff = i / 81, pp = i - ff * 81;
        y[(size_t)b * LIN + i] = f2bf(s_y[pp * 65 + ff]);
    }
}

// ---------------- k7: split-K reduce + layer2 + heads ----------------
__global__ __launch_bounds__(128) void k7_heads(
    const float* __restrict__ PART, const float* __restrict__ a1b,
    const float* __restrict__ v1b, const int* __restrict__ action,
    const float* __restrict__ a2, const float* __restrict__ a2b,
    const float* __restrict__ a3, const float* __restrict__ a3b,
    const float* __restrict__ v2, const float* __restrict__ v2b,
    const float* __restrict__ v3, const float* __restrict__ v3b,
    float* __restrict__ out)
{
    int b = blockIdx.x, tid = threadIdx.x;
    __shared__ float h1a[128], h1v[128], h2a[128], red[128];
    __shared__ float lg[5];
    float sa0 = a1b[tid], sv0 = v1b[tid];
    const float* pb = PART + (size_t)b * 256;
    for (int z = 0; z < KSPLIT; ++z) {
        sa0 += pb[(size_t)z * (BS * 256) + tid];
        sv0 += pb[(size_t)z * (BS * 256) + 128 + tid];
    }
    h1a[tid] = sa0 > 0.f ? sa0 : 0.01f * sa0;
    h1v[tid] = sv0 > 0.f ? sv0 : 0.01f * sv0;
    __syncthreads();
    float sa = a2b[tid], sv = v2b[tid];
    for (int k = 0; k < 128; ++k) {
        sa += h1a[k] * a2[k * 128 + tid];
        sv += h1v[k] * v2[k * 128 + tid];
    }
    sa = sa > 0.f ? sa : 0.01f * sa;
    sv = sv > 0.f ? sv : 0.01f * sv;
    h2a[tid] = sa;
    red[tid] = sv * v3[tid];
    __syncthreads();
    for (int s = 64; s > 0; s >>= 1) {
        if (tid < s) red[tid] += red[tid + s];
        __syncthreads();
    }
    if (tid < 5) {
        float l = a3b[tid];
        for (int k = 0; k < 128; ++k) l += h2a[k] * a3[k * 5 + tid];
        lg[tid] = l;
    }
    __syncthreads();
    if (tid == 0) {
        float m = lg[0];
        for (int j2 = 1; j2 < 5; ++j2) m = fmaxf(m, lg[j2]);
        float se = 0.f;
        for (int j2 = 0; j2 < 5; ++j2) se += expf(lg[j2] - m);
        float lse = m + logf(se);
        int act = action[b];
        float ent = 0.f;
        for (int j2 = 0; j2 < 5; ++j2) {
            float lp = lg[j2] - lse;
            ent -= expf(lp) * lp;
        }
        out[b]        = lg[act] - lse;
        out[512 + b]  = red[0] + v3b[0];
        out[1024 + b] = ent;
    }
}

// ---------------- launch ----------------
extern "C" void kernel_launch(void* const* d_in, const int* in_sizes, int n_in,
                              void* d_out, int out_size, void* d_ws, size_t ws_size,
                              hipStream_t stream)
{
    const int*   state  = (const int*)d_in[0];
    const int*   action = (const int*)d_in[1];
    const float* temb   = (const float*)d_in[2];
    const float* sprite = (const float*)d_in[3];
    const float* conv_w = (const float*)d_in[4];
    const float* conv_b = (const float*)d_in[5];
    const float* Wk     = (const float*)d_in[6];
    const float* bk     = (const float*)d_in[7];
    const float* Wks    = (const float*)d_in[8];
    const float* Wv     = (const float*)d_in[10];
    const float* bv     = (const float*)d_in[11];
    const float* Wvs    = (const float*)d_in[12];
    const float* a1     = (const float*)d_in[14];
    const float* a1b    = (const float*)d_in[15];
    const float* a2     = (const float*)d_in[16];
    const float* a2b    = (const float*)d_in[17];
    const float* a3     = (const float*)d_in[18];
    const float* a3b    = (const float*)d_in[19];
    const float* v1     = (const float*)d_in[20];
    const float* v1b    = (const float*)d_in[21];
    const float* v2     = (const float*)d_in[22];
    const float* v2b    = (const float*)d_in[23];
    const float* v3     = (const float*)d_in[24];
    const float* v3b    = (const float*)d_in[25];
    (void)in_sizes; (void)n_in; (void)out_size; (void)ws_size;

    float* ws  = (float*)d_ws;
    float* P   = ws + OFF_P;
    float* C0  = ws + OFF_C0;
    int*   FL  = (int*)(ws + OFF_FL);
    float* RD  = ws + OFF_RD;
    float* bvW2= RD + 25 * 768;
    float* DT  = ws + OFF_DT;
    short* W2T = (short*)(ws + OFF_W2T);
    short* WVH = (short*)(ws + OFF_WVH);
    short* WCT = (short*)(ws + OFF_WCT);
    short* AB  = (short*)(ws + OFF_AB);
    float* SK  = ws + OFF_SK;
    float* SV  = ws + OFF_SV;
    short* XVH = (short*)(ws + OFF_XVH);
    float* VW  = ws + OFF_VW;
    short* YH  = (short*)(ws + OFF_YH);
    float* PART= ws + OFF_PART;
    float* out = (float*)d_out;

    kA_prep<<<574, 256, 0, stream>>>(conv_w, sprite, bk, Wk, Wv, bv, a1, v1,
                                     W2T, WVH, AB, P, RD, C0, FL);
    // WCT[n_tf][d] = sum_c W2T[n_tf][c] * Wv[d][c]   (768x768, K=256) -> bf16
    gemm_mfma<0,1><<<dim3(12,12,1),256,0,stream>>>(W2T, WVH, nullptr, WCT, 256, 768, 256, 0);

    kB1_scores<<<13824, 256, 0, stream>>>(temb, Wks, Wvs, SK, SV);
    kB2_sum<<<NBS, 256, 0, stream>>>(temb, SK, SV, P, C0, XVH, DT);

    // VW = XVh @ Wcomb + bv@W2   (1536 x 768, K=768) -> fp32
    gemm_mfma<1,0><<<dim3(24,12,1),256,0,stream>>>(XVH, WCT, bvW2, VW, 768, 768, 768, 0);

    k4_y<<<BS, 256, 0, stream>>>(state, DT, FL, VW, RD, conv_b, YH);

    // PART[z] = Yh @ [a1||v1] slice  (512 x 256, K split 27x192) -> fp32
    gemm_mfma<0,0><<<dim3(8,4,KSPLIT),256,0,stream>>>(YH, AB, nullptr, PART, 5184, 256, KCH, (size_t)BS*256);

    k7_heads<<<BS, 128, 0, stream>>>(PART, a1b, v1b, action, a2, a2b, a3, a3b,
                                     v2, v2b, v3, v3b, out);
}